// Round 1
// baseline (109.938 us; speedup 1.0000x reference)
//
#include <hip/hip_runtime.h>

#define D_MODEL 2048
#define THREADS 256
#define PER_THREAD 8   // D_MODEL / THREADS

__global__ __launch_bounds__(THREADS)
void hypercube_fused_kernel(const float* __restrict__ x,
                            const float* __restrict__ W_to,
                            const float* __restrict__ W_from,
                            const float* __restrict__ log_temp,
                            const float* __restrict__ scale_p,
                            float* __restrict__ out)
{
    const int token = blockIdx.x;
    const int tid   = threadIdx.x;
    const int d0    = tid * PER_THREAD;

    const float* xt = x + (size_t)token * D_MODEL;

    // ---- load x into registers (read x exactly once from HBM) ----
    const float4 xv0 = *reinterpret_cast<const float4*>(xt + d0);
    const float4 xv1 = *reinterpret_cast<const float4*>(xt + d0 + 4);
    float xr[PER_THREAD] = {xv0.x, xv0.y, xv0.z, xv0.w,
                            xv1.x, xv1.y, xv1.z, xv1.w};

    // ---- partial projection z[k] = sum_d x[d] * W_to[k][d] ----
    float zp[4];
#pragma unroll
    for (int k = 0; k < 4; ++k) {
        const float* wk = W_to + k * D_MODEL + d0;
        const float4 w0 = *reinterpret_cast<const float4*>(wk);
        const float4 w1 = *reinterpret_cast<const float4*>(wk + 4);
        zp[k] = xr[0]*w0.x + xr[1]*w0.y + xr[2]*w0.z + xr[3]*w0.w
              + xr[4]*w1.x + xr[5]*w1.y + xr[6]*w1.z + xr[7]*w1.w;
    }

    // ---- wave64 butterfly reduce all 4 sums ----
#pragma unroll
    for (int off = 32; off >= 1; off >>= 1) {
#pragma unroll
        for (int k = 0; k < 4; ++k)
            zp[k] += __shfl_xor(zp[k], off);
    }

    // ---- cross-wave reduce via tiny LDS ----
    __shared__ float red[4][4];
    const int wave = tid >> 6;
    const int lane = tid & 63;
    if (lane == 0) {
#pragma unroll
        for (int k = 0; k < 4; ++k) red[wave][k] = zp[k];
    }
    __syncthreads();
    float z[4];
#pragma unroll
    for (int k = 0; k < 4; ++k)
        z[k] = red[0][k] + red[1][k] + red[2][k] + red[3][k];

    // ---- temp & scale scalars (broadcast loads, L2-resident) ----
    float temp = __expf(0.0f);  // placeholder to keep compiler honest
    temp = expf(log_temp[0]);
    temp = fminf(fmaxf(temp, 0.01f), 5.0f);
    const float inv_temp = 1.0f / temp;
    const float scale = scale_p[0];

    // ---- distances to 16 vertices, softmax, quantized[4] ----
    // V[k][j] = (k>>j)&1 is a k-relabeling of itertools.product order;
    // softmax+recombine is invariant to k-permutation -> exact.
    float logits[16];
    float m = -1e30f;
#pragma unroll
    for (int k = 0; k < 16; ++k) {
        float s = 0.f;
#pragma unroll
        for (int j = 0; j < 4; ++j) {
            const float dz = z[j] - (float)((k >> j) & 1);
            s += dz * dz;
        }
        logits[k] = -sqrtf(s) * inv_temp;
        m = fmaxf(m, logits[k]);
    }
    float esum = 0.f;
    float q[4] = {0.f, 0.f, 0.f, 0.f};
#pragma unroll
    for (int k = 0; k < 16; ++k) {
        const float e = expf(logits[k] - m);
        esum += e;
#pragma unroll
        for (int j = 0; j < 4; ++j)
            q[j] += e * (float)((k >> j) & 1);
    }
    const float qscale = scale / esum;
#pragma unroll
    for (int j = 0; j < 4; ++j) q[j] *= qscale;

    // ---- out[d] = x[d] + sum_k q[k] * W_from[d][k] ----
    float o[PER_THREAD];
#pragma unroll
    for (int i = 0; i < PER_THREAD; ++i) {
        const float4 wf = *reinterpret_cast<const float4*>(W_from + (size_t)(d0 + i) * 4);
        o[i] = xr[i] + q[0]*wf.x + q[1]*wf.y + q[2]*wf.z + q[3]*wf.w;
    }
    float* ot = out + (size_t)token * D_MODEL;
    *reinterpret_cast<float4*>(ot + d0)     = make_float4(o[0], o[1], o[2], o[3]);
    *reinterpret_cast<float4*>(ot + d0 + 4) = make_float4(o[4], o[5], o[6], o[7]);
}

extern "C" void kernel_launch(void* const* d_in, const int* in_sizes, int n_in,
                              void* d_out, int out_size, void* d_ws, size_t ws_size,
                              hipStream_t stream) {
    const float* x        = (const float*)d_in[0];
    const float* W_to     = (const float*)d_in[1];
    const float* W_from   = (const float*)d_in[2];
    const float* log_temp = (const float*)d_in[3];
    const float* scale    = (const float*)d_in[4];
    float* out = (float*)d_out;

    const int n_tokens = in_sizes[0] / D_MODEL;  // B*S = 16384
    hypercube_fused_kernel<<<n_tokens, THREADS, 0, stream>>>(
        x, W_to, W_from, log_temp, scale, out);
}

// Round 2
// 106.982 us; speedup vs baseline: 1.0276x; 1.0276x over previous
//
#include <hip/hip_runtime.h>

#define D_MODEL   2048
#define THREADS   256
#define NSTRIP    8          // D_MODEL / (64 lanes * 4 floats)
#define TOK_PER_WAVE 2

__global__ __launch_bounds__(THREADS)
void hypercube_fused_kernel(const float* __restrict__ x,
                            const float* __restrict__ W_to,
                            const float* __restrict__ W_from,
                            const float* __restrict__ log_temp,
                            const float* __restrict__ scale_p,
                            float* __restrict__ out,
                            int n_tokens)
{
    const int tid  = threadIdx.x;
    const int lane = tid & 63;
    const int wave = tid >> 6;

    const int tok0 = (blockIdx.x * 4 + wave) * TOK_PER_WAVE;
    if (tok0 >= n_tokens) return;

    const float4* __restrict__ X4  = reinterpret_cast<const float4*>(x);
    const float4* __restrict__ WT4 = reinterpret_cast<const float4*>(W_to);
    const float4* __restrict__ WF4 = reinterpret_cast<const float4*>(W_from);
    float4* __restrict__ O4 = reinterpret_cast<float4*>(out);

    // per-strip float4 index within a token: s*64 + lane  (d = s*256 + lane*4)
    // ---- phase 1: projection, x kept in registers ----
    float4 xv0[NSTRIP], xv1[NSTRIP];
    float zp[TOK_PER_WAVE][4] = {{0.f,0.f,0.f,0.f},{0.f,0.f,0.f,0.f}};

    const size_t xb0 = (size_t)tok0 * (D_MODEL/4);
    const size_t xb1 = xb0 + (D_MODEL/4);

#pragma unroll
    for (int s = 0; s < NSTRIP; ++s) {
        const int fi = s * 64 + lane;               // float4 index within 2048-row
        const float4 w0 = WT4[0*512 + fi];
        const float4 w1 = WT4[1*512 + fi];
        const float4 w2 = WT4[2*512 + fi];
        const float4 w3 = WT4[3*512 + fi];
        const float4 a  = X4[xb0 + fi];
        const float4 b  = X4[xb1 + fi];
        xv0[s] = a; xv1[s] = b;
        zp[0][0] += a.x*w0.x + a.y*w0.y + a.z*w0.z + a.w*w0.w;
        zp[0][1] += a.x*w1.x + a.y*w1.y + a.z*w1.z + a.w*w1.w;
        zp[0][2] += a.x*w2.x + a.y*w2.y + a.z*w2.z + a.w*w2.w;
        zp[0][3] += a.x*w3.x + a.y*w3.y + a.z*w3.z + a.w*w3.w;
        zp[1][0] += b.x*w0.x + b.y*w0.y + b.z*w0.z + b.w*w0.w;
        zp[1][1] += b.x*w1.x + b.y*w1.y + b.z*w1.z + b.w*w1.w;
        zp[1][2] += b.x*w2.x + b.y*w2.y + b.z*w2.z + b.w*w2.w;
        zp[1][3] += b.x*w3.x + b.y*w3.y + b.z*w3.z + b.w*w3.w;
    }

    // ---- wave64 butterfly reduce (8 sums), no LDS, no barrier ----
#pragma unroll
    for (int off = 32; off >= 1; off >>= 1) {
#pragma unroll
        for (int t = 0; t < TOK_PER_WAVE; ++t)
#pragma unroll
            for (int k = 0; k < 4; ++k)
                zp[t][k] += __shfl_xor(zp[t][k], off);
    }

    // ---- scalars ----
    float temp = expf(log_temp[0]);
    temp = fminf(fmaxf(temp, 0.01f), 5.0f);
    const float inv_temp = 1.0f / temp;
    const float scale = scale_p[0];

    // ---- softmax over 16 vertices, per token (all lanes redundant) ----
    float q[TOK_PER_WAVE][4];
#pragma unroll
    for (int t = 0; t < TOK_PER_WAVE; ++t) {
        float logits[16];
        float m = -1e30f;
#pragma unroll
        for (int k = 0; k < 16; ++k) {
            float ssum = 0.f;
#pragma unroll
            for (int j = 0; j < 4; ++j) {
                const float dz = zp[t][j] - (float)((k >> j) & 1);
                ssum += dz * dz;
            }
            logits[k] = -sqrtf(ssum) * inv_temp;
            m = fmaxf(m, logits[k]);
        }
        float esum = 0.f;
        float qq[4] = {0.f,0.f,0.f,0.f};
#pragma unroll
        for (int k = 0; k < 16; ++k) {
            const float e = expf(logits[k] - m);
            esum += e;
#pragma unroll
            for (int j = 0; j < 4; ++j)
                qq[j] += e * (float)((k >> j) & 1);
        }
        const float qs = scale / esum;
#pragma unroll
        for (int j = 0; j < 4; ++j) q[t][j] = qq[j] * qs;
    }

    // ---- phase 2: out = x + q . W_from^T, W_from rows shared by both tokens ----
#pragma unroll
    for (int s = 0; s < NSTRIP; ++s) {
        const int fi = s * 64 + lane;      // float4 index; row d = fi*4
        const int d  = fi * 4;
        const float4 wf0 = WF4[d + 0];     // row d   : [k0..k3]
        const float4 wf1 = WF4[d + 1];
        const float4 wf2 = WF4[d + 2];
        const float4 wf3 = WF4[d + 3];

        float4 o0, o1;
        o0.x = xv0[s].x + q[0][0]*wf0.x + q[0][1]*wf0.y + q[0][2]*wf0.z + q[0][3]*wf0.w;
        o0.y = xv0[s].y + q[0][0]*wf1.x + q[0][1]*wf1.y + q[0][2]*wf1.z + q[0][3]*wf1.w;
        o0.z = xv0[s].z + q[0][0]*wf2.x + q[0][1]*wf2.y + q[0][2]*wf2.z + q[0][3]*wf2.w;
        o0.w = xv0[s].w + q[0][0]*wf3.x + q[0][1]*wf3.y + q[0][2]*wf3.z + q[0][3]*wf3.w;
        o1.x = xv1[s].x + q[1][0]*wf0.x + q[1][1]*wf0.y + q[1][2]*wf0.z + q[1][3]*wf0.w;
        o1.y = xv1[s].y + q[1][0]*wf1.x + q[1][1]*wf1.y + q[1][2]*wf1.z + q[1][3]*wf1.w;
        o1.z = xv1[s].z + q[1][0]*wf2.x + q[1][1]*wf2.y + q[1][2]*wf2.z + q[1][3]*wf2.w;
        o1.w = xv1[s].w + q[1][0]*wf3.x + q[1][1]*wf3.y + q[1][2]*wf3.z + q[1][3]*wf3.w;

        O4[xb0 + fi] = o0;
        O4[xb1 + fi] = o1;
    }
}

extern "C" void kernel_launch(void* const* d_in, const int* in_sizes, int n_in,
                              void* d_out, int out_size, void* d_ws, size_t ws_size,
                              hipStream_t stream) {
    const float* x        = (const float*)d_in[0];
    const float* W_to     = (const float*)d_in[1];
    const float* W_from   = (const float*)d_in[2];
    const float* log_temp = (const float*)d_in[3];
    const float* scale    = (const float*)d_in[4];
    float* out = (float*)d_out;

    const int n_tokens = in_sizes[0] / D_MODEL;               // 16384
    const int tok_per_block = 4 * TOK_PER_WAVE;               // 4 waves x 2 tokens
    const int blocks = (n_tokens + tok_per_block - 1) / tok_per_block;
    hypercube_fused_kernel<<<blocks, THREADS, 0, stream>>>(
        x, W_to, W_from, log_temp, scale, out, n_tokens);
}

// Round 3
// 81.809 us; speedup vs baseline: 1.3438x; 1.3077x over previous
//
#include <hip/hip_runtime.h>

#define D_MODEL   2048
#define F4_PER_TOKEN (D_MODEL / 4)     // 512
#define THREADS   256
#define NSTRIP    8                    // D_MODEL / (64 lanes * 4 floats)
#define TOK_PER_WAVE 2
#define TOK_PER_BLOCK_K2 8

// ---------------- K1: projection + softmax -> q[token][4] (scale folded) ----
__global__ __launch_bounds__(THREADS)
void proj_q_kernel(const float* __restrict__ x,
                   const float* __restrict__ W_to,
                   const float* __restrict__ log_temp,
                   const float* __restrict__ scale_p,
                   float4* __restrict__ qout,
                   int n_tokens)
{
    const int tid  = threadIdx.x;
    const int lane = tid & 63;
    const int wave = tid >> 6;

    const int tok0 = (blockIdx.x * 4 + wave) * TOK_PER_WAVE;
    if (tok0 >= n_tokens) return;

    const float4* __restrict__ X4  = reinterpret_cast<const float4*>(x);
    const float4* __restrict__ WT4 = reinterpret_cast<const float4*>(W_to);

    const size_t xb0 = (size_t)tok0 * F4_PER_TOKEN;
    const size_t xb1 = xb0 + F4_PER_TOKEN;

    float zp[TOK_PER_WAVE][4] = {{0.f,0.f,0.f,0.f},{0.f,0.f,0.f,0.f}};

#pragma unroll
    for (int s = 0; s < NSTRIP; ++s) {
        const int fi = s * 64 + lane;
        const float4 w0 = WT4[0*512 + fi];
        const float4 w1 = WT4[1*512 + fi];
        const float4 w2 = WT4[2*512 + fi];
        const float4 w3 = WT4[3*512 + fi];
        const float4 a  = X4[xb0 + fi];
        const float4 b  = X4[xb1 + fi];
        zp[0][0] += a.x*w0.x + a.y*w0.y + a.z*w0.z + a.w*w0.w;
        zp[0][1] += a.x*w1.x + a.y*w1.y + a.z*w1.z + a.w*w1.w;
        zp[0][2] += a.x*w2.x + a.y*w2.y + a.z*w2.z + a.w*w2.w;
        zp[0][3] += a.x*w3.x + a.y*w3.y + a.z*w3.z + a.w*w3.w;
        zp[1][0] += b.x*w0.x + b.y*w0.y + b.z*w0.z + b.w*w0.w;
        zp[1][1] += b.x*w1.x + b.y*w1.y + b.z*w1.z + b.w*w1.w;
        zp[1][2] += b.x*w2.x + b.y*w2.y + b.z*w2.z + b.w*w2.w;
        zp[1][3] += b.x*w3.x + b.y*w3.y + b.z*w3.z + b.w*w3.w;
    }

    // wave64 butterfly reduction of 8 sums — no LDS, no barrier
#pragma unroll
    for (int off = 32; off >= 1; off >>= 1) {
#pragma unroll
        for (int t = 0; t < TOK_PER_WAVE; ++t)
#pragma unroll
            for (int k = 0; k < 4; ++k)
                zp[t][k] += __shfl_xor(zp[t][k], off);
    }

    float temp = expf(log_temp[0]);
    temp = fminf(fmaxf(temp, 0.01f), 5.0f);
    const float inv_temp = 1.0f / temp;
    const float scale = scale_p[0];

    float4 qv[TOK_PER_WAVE];
#pragma unroll
    for (int t = 0; t < TOK_PER_WAVE; ++t) {
        float logits[16];
        float m = -1e30f;
#pragma unroll
        for (int k = 0; k < 16; ++k) {
            float ssum = 0.f;
#pragma unroll
            for (int j = 0; j < 4; ++j) {
                const float dz = zp[t][j] - (float)((k >> j) & 1);
                ssum += dz * dz;
            }
            logits[k] = -sqrtf(ssum) * inv_temp;
            m = fmaxf(m, logits[k]);
        }
        float esum = 0.f;
        float qq[4] = {0.f,0.f,0.f,0.f};
#pragma unroll
        for (int k = 0; k < 16; ++k) {
            const float e = expf(logits[k] - m);
            esum += e;
#pragma unroll
            for (int j = 0; j < 4; ++j)
                qq[j] += e * (float)((k >> j) & 1);
        }
        const float qs = scale / esum;   // fold scale into q
        qv[t] = make_float4(qq[0]*qs, qq[1]*qs, qq[2]*qs, qq[3]*qs);
    }

    if (lane == 0) {
        qout[tok0]     = qv[0];
        qout[tok0 + 1] = qv[1];
    }
}

// ---------------- K2: out = x + q . W_from^T, W_from register-resident -----
__global__ __launch_bounds__(THREADS)
void out_kernel(const float* __restrict__ x,
                const float* __restrict__ W_from,
                const float4* __restrict__ qin,
                float* __restrict__ out,
                int n_tokens)
{
    const int tid = threadIdx.x;

    const float4* __restrict__ X4  = reinterpret_cast<const float4*>(x);
    const float4* __restrict__ WF4 = reinterpret_cast<const float4*>(W_from);
    float4* __restrict__ O4 = reinterpret_cast<float4*>(out);

    // Each thread owns 2 strips of one float4 each; W_from rows cached in regs.
    float4 wf[2][4];
#pragma unroll
    for (int st = 0; st < 2; ++st) {
        const int fi = st * 256 + tid;      // float4 index in token; d0 = fi*4
#pragma unroll
        for (int r = 0; r < 4; ++r)
            wf[st][r] = WF4[fi * 4 + r];    // row (d0+r): [k0..k3]
    }

    const int t0 = blockIdx.x * TOK_PER_BLOCK_K2;
    const int t1 = min(t0 + TOK_PER_BLOCK_K2, n_tokens);

    for (int t = t0; t < t1; ++t) {
        const float4 qv = qin[t];           // uniform -> scalar load
        const size_t base = (size_t)t * F4_PER_TOKEN;
#pragma unroll
        for (int st = 0; st < 2; ++st) {
            const int fi = st * 256 + tid;
            const float4 xv = X4[base + fi];
            float4 o;
            o.x = xv.x + qv.x*wf[st][0].x + qv.y*wf[st][0].y + qv.z*wf[st][0].z + qv.w*wf[st][0].w;
            o.y = xv.y + qv.x*wf[st][1].x + qv.y*wf[st][1].y + qv.z*wf[st][1].z + qv.w*wf[st][1].w;
            o.z = xv.z + qv.x*wf[st][2].x + qv.y*wf[st][2].y + qv.z*wf[st][2].z + qv.w*wf[st][2].w;
            o.w = xv.w + qv.x*wf[st][3].x + qv.y*wf[st][3].y + qv.z*wf[st][3].z + qv.w*wf[st][3].w;
            O4[base + fi] = o;
        }
    }
}

extern "C" void kernel_launch(void* const* d_in, const int* in_sizes, int n_in,
                              void* d_out, int out_size, void* d_ws, size_t ws_size,
                              hipStream_t stream) {
    const float* x        = (const float*)d_in[0];
    const float* W_to     = (const float*)d_in[1];
    const float* W_from   = (const float*)d_in[2];
    const float* log_temp = (const float*)d_in[3];
    const float* scale    = (const float*)d_in[4];
    float* out = (float*)d_out;
    float4* q  = (float4*)d_ws;                 // 16384 * 16 B = 256 KB

    const int n_tokens = in_sizes[0] / D_MODEL; // 16384

    const int k1_blocks = (n_tokens + 4 * TOK_PER_WAVE - 1) / (4 * TOK_PER_WAVE);
    proj_q_kernel<<<k1_blocks, THREADS, 0, stream>>>(x, W_to, log_temp, scale, q, n_tokens);

    const int k2_blocks = (n_tokens + TOK_PER_BLOCK_K2 - 1) / TOK_PER_BLOCK_K2;
    out_kernel<<<k2_blocks, THREADS, 0, stream>>>(x, W_from, q, out, n_tokens);
}

// Round 4
// 80.805 us; speedup vs baseline: 1.3605x; 1.0124x over previous
//
#include <hip/hip_runtime.h>

#define D_MODEL   2048
#define F4T       (D_MODEL / 4)        // 512 float4 per token
#define THREADS   256
#define NSTRIP    8                    // D_MODEL / (64 lanes * 4 floats)
#define TOK_PER_WAVE 2
#define K2_TOK    16                   // tokens per block in K2
#define K2_CHUNK  4

typedef float f4 __attribute__((ext_vector_type(4)));

// ---------------- K1: projection + softmax -> q[token][4] (scale folded) ----
__global__ __launch_bounds__(THREADS)
void proj_q_kernel(const float* __restrict__ x,
                   const float* __restrict__ W_to,
                   const float* __restrict__ log_temp,
                   const float* __restrict__ scale_p,
                   f4* __restrict__ qout,
                   int n_tokens)
{
    const int tid  = threadIdx.x;
    const int lane = tid & 63;
    const int wave = tid >> 6;

    const int tok0 = (blockIdx.x * 4 + wave) * TOK_PER_WAVE;
    if (tok0 >= n_tokens) return;

    const f4* __restrict__ X4  = reinterpret_cast<const f4*>(x);
    const f4* __restrict__ WT4 = reinterpret_cast<const f4*>(W_to);

    const size_t xb0 = (size_t)tok0 * F4T;
    const size_t xb1 = xb0 + F4T;

    float zp[TOK_PER_WAVE][4] = {{0.f,0.f,0.f,0.f},{0.f,0.f,0.f,0.f}};

#pragma unroll
    for (int s = 0; s < NSTRIP; ++s) {
        const int fi = s * 64 + lane;
        const f4 w0 = WT4[0*512 + fi];
        const f4 w1 = WT4[1*512 + fi];
        const f4 w2 = WT4[2*512 + fi];
        const f4 w3 = WT4[3*512 + fi];
        const f4 a  = X4[xb0 + fi];
        const f4 b  = X4[xb1 + fi];
        zp[0][0] += a.x*w0.x + a.y*w0.y + a.z*w0.z + a.w*w0.w;
        zp[0][1] += a.x*w1.x + a.y*w1.y + a.z*w1.z + a.w*w1.w;
        zp[0][2] += a.x*w2.x + a.y*w2.y + a.z*w2.z + a.w*w2.w;
        zp[0][3] += a.x*w3.x + a.y*w3.y + a.z*w3.z + a.w*w3.w;
        zp[1][0] += b.x*w0.x + b.y*w0.y + b.z*w0.z + b.w*w0.w;
        zp[1][1] += b.x*w1.x + b.y*w1.y + b.z*w1.z + b.w*w1.w;
        zp[1][2] += b.x*w2.x + b.y*w2.y + b.z*w2.z + b.w*w2.w;
        zp[1][3] += b.x*w3.x + b.y*w3.y + b.z*w3.z + b.w*w3.w;
    }

    // wave64 butterfly reduction of 8 sums — no LDS, no barrier
#pragma unroll
    for (int off = 32; off >= 1; off >>= 1) {
#pragma unroll
        for (int t = 0; t < TOK_PER_WAVE; ++t)
#pragma unroll
            for (int k = 0; k < 4; ++k)
                zp[t][k] += __shfl_xor(zp[t][k], off);
    }

    float temp = expf(log_temp[0]);
    temp = fminf(fmaxf(temp, 0.01f), 5.0f);
    const float inv_temp = 1.0f / temp;
    const float scale = scale_p[0];

    f4 qv[TOK_PER_WAVE];
#pragma unroll
    for (int t = 0; t < TOK_PER_WAVE; ++t) {
        float logits[16];
        float m = -1e30f;
#pragma unroll
        for (int k = 0; k < 16; ++k) {
            float ssum = 0.f;
#pragma unroll
            for (int j = 0; j < 4; ++j) {
                const float dz = zp[t][j] - (float)((k >> j) & 1);
                ssum += dz * dz;
            }
            logits[k] = -sqrtf(ssum) * inv_temp;
            m = fmaxf(m, logits[k]);
        }
        float esum = 0.f;
        float qq[4] = {0.f,0.f,0.f,0.f};
#pragma unroll
        for (int k = 0; k < 16; ++k) {
            const float e = expf(logits[k] - m);
            esum += e;
#pragma unroll
            for (int j = 0; j < 4; ++j)
                qq[j] += e * (float)((k >> j) & 1);
        }
        const float qs = scale / esum;   // fold scale into q
        f4 o; o.x = qq[0]*qs; o.y = qq[1]*qs; o.z = qq[2]*qs; o.w = qq[3]*qs;
        qv[t] = o;
    }

    if (lane == 0) {
        qout[tok0]     = qv[0];
        qout[tok0 + 1] = qv[1];
    }
}

// ---------------- K2: out = x + q . W_from^T ------------------------------
// 1 float4 per thread per token; 16 tokens/block; chunk-4 batched loads for
// MLP; nontemporal stores keep x L3-resident.
__global__ __launch_bounds__(THREADS)
void out_kernel(const float* __restrict__ x,
                const float* __restrict__ W_from,
                const f4* __restrict__ qin,
                float* __restrict__ out,
                int n_tokens)
{
    const int tid = threadIdx.x;
    const int fi  = blockIdx.y * THREADS + tid;   // float4 index within token

    const f4* __restrict__ X4  = reinterpret_cast<const f4*>(x);
    const f4* __restrict__ WF4 = reinterpret_cast<const f4*>(W_from);
    f4* __restrict__ O4 = reinterpret_cast<f4*>(out);

    // W_from rows 4*fi .. 4*fi+3, register-resident across all 16 tokens
    const f4 wf0 = WF4[fi*4 + 0];
    const f4 wf1 = WF4[fi*4 + 1];
    const f4 wf2 = WF4[fi*4 + 2];
    const f4 wf3 = WF4[fi*4 + 3];

    const int t0 = blockIdx.x * K2_TOK;

#pragma unroll 1
    for (int tb = 0; tb < K2_TOK; tb += K2_CHUNK) {
        f4 qv[K2_CHUNK], xv[K2_CHUNK];
#pragma unroll
        for (int u = 0; u < K2_CHUNK; ++u) {
            const int t = t0 + tb + u;
            qv[u] = qin[t];
            xv[u] = X4[(size_t)t * F4T + fi];
        }
#pragma unroll
        for (int u = 0; u < K2_CHUNK; ++u) {
            const int t = t0 + tb + u;
            f4 o;
            o.x = xv[u].x + qv[u].x*wf0.x + qv[u].y*wf0.y + qv[u].z*wf0.z + qv[u].w*wf0.w;
            o.y = xv[u].y + qv[u].x*wf1.x + qv[u].y*wf1.y + qv[u].z*wf1.z + qv[u].w*wf1.w;
            o.z = xv[u].z + qv[u].x*wf2.x + qv[u].y*wf2.y + qv[u].z*wf2.z + qv[u].w*wf2.w;
            o.w = xv[u].w + qv[u].x*wf3.x + qv[u].y*wf3.y + qv[u].z*wf3.z + qv[u].w*wf3.w;
            __builtin_nontemporal_store(o, &O4[(size_t)t * F4T + fi]);
        }
    }
}

extern "C" void kernel_launch(void* const* d_in, const int* in_sizes, int n_in,
                              void* d_out, int out_size, void* d_ws, size_t ws_size,
                              hipStream_t stream) {
    const float* x        = (const float*)d_in[0];
    const float* W_to     = (const float*)d_in[1];
    const float* W_from   = (const float*)d_in[2];
    const float* log_temp = (const float*)d_in[3];
    const float* scale    = (const float*)d_in[4];
    float* out = (float*)d_out;
    f4* q = (f4*)d_ws;                              // 16384 * 16 B = 256 KB

    const int n_tokens = in_sizes[0] / D_MODEL;     // 16384

    const int k1_blocks = (n_tokens + 4 * TOK_PER_WAVE - 1) / (4 * TOK_PER_WAVE);
    proj_q_kernel<<<k1_blocks, THREADS, 0, stream>>>(x, W_to, log_temp, scale, q, n_tokens);

    dim3 k2_grid((n_tokens + K2_TOK - 1) / K2_TOK, D_MODEL / (4 * THREADS));  // (1024, 2)
    out_kernel<<<k2_grid, THREADS, 0, stream>>>(x, W_from, q, out, n_tokens);
}

// Round 5
// 65.505 us; speedup vs baseline: 1.6783x; 1.2336x over previous
//
#include <hip/hip_runtime.h>

#define D_MODEL   2048
#define F4T       (D_MODEL / 4)        // 512 float4 per token
#define THREADS   256
#define NSTRIP    8                    // D_MODEL / (64 lanes * 4 floats)

typedef float f4 __attribute__((ext_vector_type(4)));

// Fused: one wave per token. x read from HBM exactly once (held in VGPRs),
// W_to/W_from served from L2, out written nontemporally.
__global__ __launch_bounds__(THREADS, 4)
void hypercube_fused_kernel(const float* __restrict__ x,
                            const float* __restrict__ W_to,
                            const float* __restrict__ W_from,
                            const float* __restrict__ log_temp,
                            const float* __restrict__ scale_p,
                            float* __restrict__ out,
                            int n_tokens)
{
    const int tid   = threadIdx.x;
    const int lane  = tid & 63;
    const int wave  = tid >> 6;
    const int token = blockIdx.x * 4 + wave;
    if (token >= n_tokens) return;

    const f4* __restrict__ X4  = reinterpret_cast<const f4*>(x);
    const f4* __restrict__ WT4 = reinterpret_cast<const f4*>(W_to);
    const f4* __restrict__ WF4 = reinterpret_cast<const f4*>(W_from);
    f4* __restrict__ O4 = reinterpret_cast<f4*>(out);

    const size_t xb = (size_t)token * F4T;

    // ---- issue ALL x loads first (independent, fill the memory pipe) ----
    f4 xr[NSTRIP];
#pragma unroll
    for (int s = 0; s < NSTRIP; ++s)
        xr[s] = X4[xb + s * 64 + lane];

    // ---- projection: z[k] = sum_d x[d]*W_to[k][d]; W_to from L2 ----
    float z[4] = {0.f, 0.f, 0.f, 0.f};
#pragma unroll
    for (int s = 0; s < NSTRIP; ++s) {
        const int fi = s * 64 + lane;
        const f4 w0 = WT4[0*512 + fi];
        const f4 w1 = WT4[1*512 + fi];
        const f4 w2 = WT4[2*512 + fi];
        const f4 w3 = WT4[3*512 + fi];
        const f4 a  = xr[s];
        z[0] += a.x*w0.x + a.y*w0.y + a.z*w0.z + a.w*w0.w;
        z[1] += a.x*w1.x + a.y*w1.y + a.z*w1.z + a.w*w1.w;
        z[2] += a.x*w2.x + a.y*w2.y + a.z*w2.z + a.w*w2.w;
        z[3] += a.x*w3.x + a.y*w3.y + a.z*w3.z + a.w*w3.w;
    }

    // ---- wave64 butterfly reduce (4 sums) — no LDS, no barrier ----
#pragma unroll
    for (int off = 32; off >= 1; off >>= 1) {
#pragma unroll
        for (int k = 0; k < 4; ++k)
            z[k] += __shfl_xor(z[k], off);
    }

    // ---- scalars ----
    float temp = expf(log_temp[0]);
    temp = fminf(fmaxf(temp, 0.01f), 5.0f);
    const float inv_temp = 1.0f / temp;
    const float scale = scale_p[0];

    // ---- softmax over 16 hypercube vertices (all lanes redundant) ----
    float logits[16];
    float m = -1e30f;
#pragma unroll
    for (int k = 0; k < 16; ++k) {
        float ssum = 0.f;
#pragma unroll
        for (int j = 0; j < 4; ++j) {
            const float dz = z[j] - (float)((k >> j) & 1);
            ssum += dz * dz;
        }
        logits[k] = -sqrtf(ssum) * inv_temp;
        m = fmaxf(m, logits[k]);
    }
    float esum = 0.f;
    float qq[4] = {0.f, 0.f, 0.f, 0.f};
#pragma unroll
    for (int k = 0; k < 16; ++k) {
        const float e = expf(logits[k] - m);
        esum += e;
#pragma unroll
        for (int j = 0; j < 4; ++j)
            qq[j] += e * (float)((k >> j) & 1);
    }
    const float qs = scale / esum;
    const float q0 = qq[0]*qs, q1 = qq[1]*qs, q2 = qq[2]*qs, q3 = qq[3]*qs;

    // ---- phase 2: out = x + q . W_from^T; x from regs, W_from from L2 ----
#pragma unroll
    for (int s = 0; s < NSTRIP; ++s) {
        const int fi = s * 64 + lane;
        const int d  = fi * 4;
        const f4 wf0 = WF4[d + 0];
        const f4 wf1 = WF4[d + 1];
        const f4 wf2 = WF4[d + 2];
        const f4 wf3 = WF4[d + 3];
        f4 o;
        o.x = xr[s].x + q0*wf0.x + q1*wf0.y + q2*wf0.z + q3*wf0.w;
        o.y = xr[s].y + q0*wf1.x + q1*wf1.y + q2*wf1.z + q3*wf1.w;
        o.z = xr[s].z + q0*wf2.x + q1*wf2.y + q2*wf2.z + q3*wf2.w;
        o.w = xr[s].w + q0*wf3.x + q1*wf3.y + q2*wf3.z + q3*wf3.w;
        __builtin_nontemporal_store(o, &O4[xb + fi]);
    }
}

extern "C" void kernel_launch(void* const* d_in, const int* in_sizes, int n_in,
                              void* d_out, int out_size, void* d_ws, size_t ws_size,
                              hipStream_t stream) {
    const float* x        = (const float*)d_in[0];
    const float* W_to     = (const float*)d_in[1];
    const float* W_from   = (const float*)d_in[2];
    const float* log_temp = (const float*)d_in[3];
    const float* scale    = (const float*)d_in[4];
    float* out = (float*)d_out;

    const int n_tokens = in_sizes[0] / D_MODEL;       // 16384
    const int blocks = (n_tokens + 3) / 4;            // 4 waves/block, 1 token/wave
    hypercube_fused_kernel<<<blocks, THREADS, 0, stream>>>(
        x, W_to, W_from, log_temp, scale, out, n_tokens);
}